// Round 7
// baseline (207.059 us; speedup 1.0000x reference)
//
#include <hip/hip_runtime.h>

#define TLEN    6000
#define NV4     1500        // float4 groups per series
#define CH_V4   512         // float4 per chunk = 2048 elements
#define SUB_V4  64          // float4 per sub-chunk = 256 elements
#define NSUB    8           // sub-chunks per chunk
#define EPS     1e-6f
#define LN_EPS  (-13.815511f) // ln(1e-6)
#define INV_EPS 1e6f

__device__ __forceinline__ float pcen_full(float xv, float M, float alpha,
                                           float delta, float r, float deltar) {
    float gain = __expf(-alpha * (LN_EPS + __logf(fmaf(M, INV_EPS, 1.0f))));
    return __powf(fmaf(xv, gain, delta), r) - deltar;
}

// b^e for integer e in [0,63]
__device__ __forceinline__ float ipow6(float b, int e) {
    float r = 1.0f;
    #pragma unroll
    for (int i = 0; i < 6; ++i) {
        if (e & 1) r *= b;
        b *= b;
        e >>= 1;
    }
    return r;
}

// One 2048-elem chunk, interleaved layout: q[j] = xb[cb + 64*j + lane].
// Sub-chunk j (256 elems): lane L owns times [256j + 4L, 256j + 4L + 4).
// Per-lane decay = oms4 (constant) -> constant-coefficient Kogge-Stone.
// Serial DS rounds per chunk: 6 scan levels + 1 (T) + 1 (Be) = 8
// (the old per-sub serial carry chain is replaced by a parallel T-round
// + pure-FMA prefix). Returns exact carry into the next chunk.
template<bool PARTIAL>
__device__ __forceinline__ float chunk_compute(
    const float4 (&q)[NSUB], const int cb, const int lane, const bool finit,
    const float s, const float oms, const float oms4, const float Apow4,
    const float A256, const bool triv,
    const float la, const float ld, const float lr,
    float Mc, float4* __restrict__ ob)
{
    // per-lane affine offsets (coefficient 1 only at global t=0)
    float S[NSUB];
    #pragma unroll
    for (int j = 0; j < NSUB; ++j) {
        const float c0 = (finit && j == 0 && lane == 0) ? 1.0f : s;
        float b = c0 * q[j].x;
        b = fmaf(oms, b, s * q[j].y);
        b = fmaf(oms, b, s * q[j].z);
        b = fmaf(oms, b, s * q[j].w);
        S[j] = b;
    }

    // 8 independent Kogge-Stone scans, interleaved per level (8-wide ILP)
    float w = oms4;
    #pragma unroll
    for (int off = 1; off < 64; off <<= 1) {
        #pragma unroll
        for (int j = 0; j < NSUB; ++j) {
            const float Sp = __shfl_up(S[j], off, 64);
            if (lane >= off) S[j] = fmaf(w, Sp, S[j]);
        }
        w *= w;
    }

    // parallel carry: one shuffle round, then a pure-FMA prefix chain
    float T[NSUB];
    #pragma unroll
    for (int j = 0; j < NSUB; ++j) T[j] = __shfl(S[j], 63, 64);
    float P[NSUB + 1];
    P[0] = Mc;
    #pragma unroll
    for (int j = 0; j < NSUB; ++j) P[j + 1] = fmaf(A256, P[j], T[j]);

    // epilogue: entering value per sub-chunk, rerun recurrence, store
    if (triv) {
        // alpha=delta=r=1  =>  out = x / (eps + M)
        #pragma unroll
        for (int j = 0; j < NSUB; ++j) {
            const int vi = cb + SUB_V4 * j + lane;
            const float Se = __shfl_up(S[j], 1, 64);       // all lanes active here
            const float Be = (lane == 0) ? 0.0f : Se;
            float m = fmaf(Apow4, P[j], Be);
            if (!PARTIAL || vi < NV4) {
                const float c0 = (finit && j == 0 && lane == 0) ? 1.0f : s;
                float4 o;
                m = fmaf(oms, m, c0 * q[j].x); o.x = q[j].x * __builtin_amdgcn_rcpf(m + EPS);
                m = fmaf(oms, m, s  * q[j].y); o.y = q[j].y * __builtin_amdgcn_rcpf(m + EPS);
                m = fmaf(oms, m, s  * q[j].z); o.z = q[j].z * __builtin_amdgcn_rcpf(m + EPS);
                m = fmaf(oms, m, s  * q[j].w); o.w = q[j].w * __builtin_amdgcn_rcpf(m + EPS);
                ob[vi] = o;
            }
        }
    } else {
        const float alpha  = __expf(la);
        const float delta  = __expf(ld);
        const float r      = __expf(lr);
        const float deltar = __powf(delta, lr == 0.0f ? 1.0f : r);
        #pragma unroll
        for (int j = 0; j < NSUB; ++j) {
            const int vi = cb + SUB_V4 * j + lane;
            const float Se = __shfl_up(S[j], 1, 64);
            const float Be = (lane == 0) ? 0.0f : Se;
            float m = fmaf(Apow4, P[j], Be);
            if (!PARTIAL || vi < NV4) {
                const float c0 = (finit && j == 0 && lane == 0) ? 1.0f : s;
                float4 o;
                m = fmaf(oms, m, c0 * q[j].x); o.x = pcen_full(q[j].x, m, alpha, delta, r, deltar);
                m = fmaf(oms, m, s  * q[j].y); o.y = pcen_full(q[j].y, m, alpha, delta, r, deltar);
                m = fmaf(oms, m, s  * q[j].z); o.z = pcen_full(q[j].z, m, alpha, delta, r, deltar);
                m = fmaf(oms, m, s  * q[j].w); o.w = pcen_full(q[j].w, m, alpha, delta, r, deltar);
                ob[vi] = o;
            }
        }
    }
    return P[NSUB];
}

// ONE WAVE PER SERIES, 3 chunks of 2048: exact carry end-to-end, zero
// warm-up reads. Serial DS rounds/wave: 3x8=24 (was 6x11=66 in r4).
// waves_per_eu(4,4): pins allocator to the full 128-VGPR budget — r6
// showed the backend spills (~13 MB scratch) to squeeze 64 VGPR / 8 waves
// when left free. Post-mortem checks: VGPR ~95-120, WRITE_SIZE ~96 MB.
__global__ __launch_bounds__(256)
__attribute__((amdgpu_waves_per_eu(4, 4)))
void pcen_kernel(
    const float* __restrict__ x,
    const float* __restrict__ log_s,
    const float* __restrict__ log_alpha,
    const float* __restrict__ log_delta,
    const float* __restrict__ log_r,
    float* __restrict__ out,
    int num_series, int F)
{
    const int g    = (int)((blockIdx.x * blockDim.x + threadIdx.x) >> 6);
    const int lane = (int)(threadIdx.x & 63);
    if (g >= num_series) return;
    const int f = g % F;

    const float la = log_alpha[f], ld = log_delta[f], lr = log_r[f];
    const bool  triv = (la == 0.0f) && (ld == 0.0f) && (lr == 0.0f);

    const float s    = __expf(log_s[f]);
    const float oms  = 1.0f - s;
    const float oms2 = oms * oms;
    const float oms4 = oms2 * oms2;    // per-lane (4-elem) decay

    // A256 = oms4^64 = oms^256 (sub-chunk decay)
    float A256 = oms4;
    #pragma unroll
    for (int i = 0; i < 6; ++i) A256 *= A256;

    const float Apow4 = ipow6(oms4, lane);   // oms4^lane

    const float4* __restrict__ xb = (const float4*)(x + (size_t)g * TLEN);
    float4* __restrict__ ob       = (float4*)(out + (size_t)g * TLEN);

    float4 bufA[NSUB], bufB[NSUB];

    // prologue: chunk 0 and chunk 1 loads in flight (both fully in-bounds)
    #pragma unroll
    for (int j = 0; j < NSUB; ++j) bufA[j] = xb[SUB_V4 * j + lane];
    #pragma unroll
    for (int j = 0; j < NSUB; ++j) bufB[j] = xb[CH_V4 + SUB_V4 * j + lane];

    float Mc = 0.0f;

    // chunk 0 (chunk-1 loads remain in flight during this compute)
    Mc = chunk_compute<false>(bufA, 0, lane, true,
                              s, oms, oms4, Apow4, A256, triv, la, ld, lr, Mc, ob);

    // prefetch chunk 2 (partial: float4 idx 1024..1535, valid < 1500)
    #pragma unroll
    for (int j = 0; j < NSUB; ++j) {
        const int vi = 2 * CH_V4 + SUB_V4 * j + lane;
        bufA[j] = (vi < NV4) ? xb[vi] : make_float4(0.f, 0.f, 0.f, 0.f);
    }

    // chunk 1 (chunk-2 loads in flight)
    Mc = chunk_compute<false>(bufB, CH_V4, lane, false,
                              s, oms, oms4, Apow4, A256, triv, la, ld, lr, Mc, ob);

    // chunk 2 (tail — carry unused)
    chunk_compute<true>(bufA, 2 * CH_V4, lane, false,
                        s, oms, oms4, Apow4, A256, triv, la, ld, lr, Mc, ob);
}

extern "C" void kernel_launch(void* const* d_in, const int* in_sizes, int n_in,
                              void* d_out, int out_size, void* d_ws, size_t ws_size,
                              hipStream_t stream) {
    const float* x         = (const float*)d_in[0];
    const float* log_s     = (const float*)d_in[1];
    const float* log_alpha = (const float*)d_in[2];
    const float* log_delta = (const float*)d_in[3];
    const float* log_r     = (const float*)d_in[4];
    float* out             = (float*)d_out;

    const int F = in_sizes[1];                  // 128 bands
    const int num_series = in_sizes[0] / TLEN;  // 4096
    const int num_waves  = num_series;          // one wave per series
    const int num_threads = num_waves * 64;
    const int grid = (num_threads + 255) / 256;

    pcen_kernel<<<grid, 256, 0, stream>>>(x, log_s, log_alpha, log_delta, log_r,
                                          out, num_series, F);
}

// Round 8
// 192.126 us; speedup vs baseline: 1.0777x; 1.0777x over previous
//
#include <hip/hip_runtime.h>

#define TLEN    6000
#define NV4     1500        // float4 groups per series
#define SUB_V4  64          // float4 per sub-chunk = 256 elements
#define NSUB    12          // sub-chunks per half (12th partial for h==1)
#define H0_V4   768         // float4s in first half [0,768); second = [768,1500)
#define WARM_V4 256         // warm-up window = 1024 elements
#define EPS     1e-6f
#define LN_EPS  (-13.815511f) // ln(1e-6)
#define INV_EPS 1e6f

__device__ __forceinline__ float pcen_full(float xv, float M, float alpha,
                                           float delta, float r, float deltar) {
    float gain = __expf(-alpha * (LN_EPS + __logf(fmaf(M, INV_EPS, 1.0f))));
    return __powf(fmaf(xv, gain, delta), r) - deltar;
}

// b^e for integer e in [0,63]
__device__ __forceinline__ float ipow6(float b, int e) {
    float r = 1.0f;
    #pragma unroll
    for (int i = 0; i < 6; ++i) {
        if (e & 1) r *= b;
        b *= b;
        e >>= 1;
    }
    return r;
}

// ONE WAVE PER HALF-SERIES, TWO-PASS STREAMING.
// Pass 1 streams all 12 sub-chunks (load -> 4 FMA -> discard) so loads run
// back-to-back many-deep; pass 2 re-loads (L1/L2-hot, CSE defeated by index
// laundering) and streams the epilogue + stores. No float4 buffer arrays:
// live VGPR set stays ~55, under the allocator's empirical 64-reg wall
// (r1/r5/r6/r7 all spilled when >64 regs were needed, under every hint).
__global__ __launch_bounds__(256, 4) void pcen_kernel(
    const float* __restrict__ x,
    const float* __restrict__ log_s,
    const float* __restrict__ log_alpha,
    const float* __restrict__ log_delta,
    const float* __restrict__ log_r,
    float* __restrict__ out,
    int num_series, int F)
{
    const int g    = (int)((blockIdx.x * blockDim.x + threadIdx.x) >> 6);
    const int lane = (int)(threadIdx.x & 63);
    if (g >= num_series * 2) return;
    const int series = g >> 1;
    const int h      = g & 1;
    const int f      = series % F;

    const float la = log_alpha[f], ld = log_delta[f], lr = log_r[f];
    const bool  triv = (la == 0.0f) && (ld == 0.0f) && (lr == 0.0f);

    const float s    = __expf(log_s[f]);
    const float oms  = 1.0f - s;
    const float oms2 = oms * oms;
    const float oms4 = oms2 * oms2;        // per-lane (4-elem) decay

    // A256 = oms4^64 = oms^256 (sub-chunk decay)
    float A256 = oms4;
    #pragma unroll
    for (int i = 0; i < 6; ++i) A256 *= A256;

    const float Apow4 = ipow6(oms4, lane); // oms4^lane

    const float4* __restrict__ xb = (const float4*)(x + (size_t)series * TLEN);
    float4* __restrict__ ob       = (float4*)(out + (size_t)series * TLEN);

    const int base = h * H0_V4;            // 0 or 768

    // ---- half-boundary warm-up (h==1 only): seed Mc = M entering elem 3072 ----
    float Mc = 0.0f;
    if (h == 1) {
        const float wl = ipow6(oms4, 63 - lane);
        float A1024 = A256 * A256; A1024 *= A1024;
        if (fabsf(A1024) < 1e-7f) {
            // one warm chunk: elements [2048, 3072) — 4 streaming sub-chunks
            float Bw[4];
            #pragma unroll
            for (int k = 0; k < 4; ++k) {
                const float4 qw = xb[(H0_V4 - WARM_V4) + SUB_V4 * k + lane];
                float b = s * qw.x;
                b = fmaf(oms, b, s * qw.y);
                b = fmaf(oms, b, s * qw.z);
                b = fmaf(oms, b, s * qw.w);
                Bw[k] = b;
            }
            float v = wl * fmaf(A256, fmaf(A256, fmaf(A256, Bw[0], Bw[1]), Bw[2]), Bw[3]);
            #pragma unroll
            for (int off = 1; off < 64; off <<= 1) v += __shfl_xor(v, off, 64);
            Mc = v;
        } else {
            // exact fallback: accumulate the entire first half (12 sub-chunks)
            for (int k = 0; k < NSUB; ++k) {
                const float4 qw = xb[SUB_V4 * k + lane];
                const float c0 = (k == 0 && lane == 0) ? 1.0f : s;
                float b = c0 * qw.x;
                b = fmaf(oms, b, s * qw.y);
                b = fmaf(oms, b, s * qw.z);
                b = fmaf(oms, b, s * qw.w);
                float v = wl * b;
                #pragma unroll
                for (int off = 1; off < 64; off <<= 1) v += __shfl_xor(v, off, 64);
                Mc = fmaf(A256, Mc, v);
            }
        }
    }

    // ---- pass 1: streaming B-phase (load -> chain -> discard), 12 sub-chunks ----
    float S[NSUB];
    #pragma unroll
    for (int j = 0; j < NSUB; ++j) {
        const int vi = base + SUB_V4 * j + lane;
        const float4 q = (vi < NV4) ? xb[vi] : make_float4(0.f, 0.f, 0.f, 0.f);
        const float c0 = (h == 0 && j == 0 && lane == 0) ? 1.0f : s;
        float b = c0 * q.x;
        b = fmaf(oms, b, s * q.y);
        b = fmaf(oms, b, s * q.z);
        b = fmaf(oms, b, s * q.w);
        S[j] = b;
    }

    // ---- 12 independent constant-coefficient Kogge-Stone scans ----
    float w = oms4;
    #pragma unroll
    for (int off = 1; off < 64; off <<= 1) {
        #pragma unroll
        for (int j = 0; j < NSUB; ++j) {
            const float Sp = __shfl_up(S[j], off, 64);
            if (lane >= off) S[j] = fmaf(w, Sp, S[j]);
        }
        w *= w;
    }

    // ---- parallel carry round + pure-FMA prefix: P[j] = M entering sub-chunk j ----
    float T[NSUB - 1];
    #pragma unroll
    for (int j = 0; j < NSUB - 1; ++j) T[j] = __shfl(S[j], 63, 64);
    float P[NSUB];
    P[0] = Mc;
    #pragma unroll
    for (int j = 1; j < NSUB; ++j) P[j] = fmaf(A256, P[j - 1], T[j - 1]);

    // ---- pass 2: streaming reload + epilogue + store ----
    if (triv) {
        // alpha=delta=r=1  =>  out = x / (eps + M)
        #pragma unroll
        for (int j = 0; j < NSUB; ++j) {
            int vi = base + SUB_V4 * j + lane;
            const float Se = __shfl_up(S[j], 1, 64);     // all lanes participate
            const float Be = (lane == 0) ? 0.0f : Se;
            float m = fmaf(Apow4, P[j], Be);
            int vi2 = vi;
            asm volatile("" : "+v"(vi2));                // defeat CSE with pass-1 loads
            if (vi2 < NV4) {
                const float4 q = xb[vi2];
                const float c0 = (h == 0 && j == 0 && lane == 0) ? 1.0f : s;
                float4 o;
                m = fmaf(oms, m, c0 * q.x); o.x = q.x * __builtin_amdgcn_rcpf(m + EPS);
                m = fmaf(oms, m, s  * q.y); o.y = q.y * __builtin_amdgcn_rcpf(m + EPS);
                m = fmaf(oms, m, s  * q.z); o.z = q.z * __builtin_amdgcn_rcpf(m + EPS);
                m = fmaf(oms, m, s  * q.w); o.w = q.w * __builtin_amdgcn_rcpf(m + EPS);
                ob[vi2] = o;
            }
        }
    } else {
        const float alpha  = __expf(la);
        const float delta  = __expf(ld);
        const float r      = __expf(lr);
        const float deltar = __powf(delta, lr == 0.0f ? 1.0f : r);
        #pragma unroll
        for (int j = 0; j < NSUB; ++j) {
            int vi = base + SUB_V4 * j + lane;
            const float Se = __shfl_up(S[j], 1, 64);
            const float Be = (lane == 0) ? 0.0f : Se;
            float m = fmaf(Apow4, P[j], Be);
            int vi2 = vi;
            asm volatile("" : "+v"(vi2));
            if (vi2 < NV4) {
                const float4 q = xb[vi2];
                const float c0 = (h == 0 && j == 0 && lane == 0) ? 1.0f : s;
                float4 o;
                m = fmaf(oms, m, c0 * q.x); o.x = pcen_full(q.x, m, alpha, delta, r, deltar);
                m = fmaf(oms, m, s  * q.y); o.y = pcen_full(q.y, m, alpha, delta, r, deltar);
                m = fmaf(oms, m, s  * q.z); o.z = pcen_full(q.z, m, alpha, delta, r, deltar);
                m = fmaf(oms, m, s  * q.w); o.w = pcen_full(q.w, m, alpha, delta, r, deltar);
                ob[vi2] = o;
            }
        }
    }
}

extern "C" void kernel_launch(void* const* d_in, const int* in_sizes, int n_in,
                              void* d_out, int out_size, void* d_ws, size_t ws_size,
                              hipStream_t stream) {
    const float* x         = (const float*)d_in[0];
    const float* log_s     = (const float*)d_in[1];
    const float* log_alpha = (const float*)d_in[2];
    const float* log_delta = (const float*)d_in[3];
    const float* log_r     = (const float*)d_in[4];
    float* out             = (float*)d_out;

    const int F = in_sizes[1];                  // 128 bands
    const int num_series = in_sizes[0] / TLEN;  // 4096
    const int num_waves  = num_series * 2;      // one wave per half-series
    const int num_threads = num_waves * 64;
    const int grid = (num_threads + 255) / 256;

    pcen_kernel<<<grid, 256, 0, stream>>>(x, log_s, log_alpha, log_delta, log_r,
                                          out, num_series, F);
}

// Round 10
// 178.959 us; speedup vs baseline: 1.1570x; 1.0736x over previous
//
#include <hip/hip_runtime.h>

#define TLEN     6000
#define NV4      1500        // float4 groups per series
#define CHUNK_V4 256         // float4 per chunk = 1024 elements
#define SUB_V4   64          // float4 per sub-chunk = 256 elements
#define NCHUNK   6           // chunks per series (last partial)
#define EPS      1e-6f
#define LN_EPS   (-13.815511f) // ln(1e-6)
#define INV_EPS  1e6f

__device__ __forceinline__ float pcen_full(float xv, float M, float alpha,
                                           float delta, float r, float deltar) {
    float gain = __expf(-alpha * (LN_EPS + __logf(fmaf(M, INV_EPS, 1.0f))));
    return __powf(fmaf(xv, gain, delta), r) - deltar;
}

// b^e for integer e in [0,63]
__device__ __forceinline__ float ipow6(float b, int e) {
    float r = 1.0f;
    #pragma unroll
    for (int i = 0; i < 6; ++i) {
        if (e & 1) r *= b;
        b *= b;
        e >>= 1;
    }
    return r;
}

// ONE WAVE PER 1024-ELEM CHUNK (24576 independent waves — r0's geometry),
// with the interleaved coalesced layout (r4) and parallel carry (r7):
//  - all 8 loads (warm chunk + main chunk, 1 KB each) issued in one burst
//    before any dependent compute -> max independent requests in flight;
//  - warm butterfly-reduce (6 rounds) and main Kogge-Stone (6 rounds) are
//    data-independent -> 5-wide ILP on the DS pipe, ~14 serial rounds total;
//  - 96 waves/CU of work keeps residency pinned at cap for the whole
//    dispatch (no drain tail), unlike the 8k/4k-wave variants.
// Interleaved layout: sub-chunk j of a chunk: lane L owns times
// [cb*4 + 256j + 4L, +4). Loads/stores are lane-contiguous (1 KB/instr).
// VGPR budget ~55 (< the allocator's empirical 64-reg wall; launch_bounds
// (256,4) is the only hint that has never mis-allocated here).
__global__ __launch_bounds__(256, 4) void pcen_kernel(
    const float* __restrict__ x,
    const float* __restrict__ log_s,
    const float* __restrict__ log_alpha,
    const float* __restrict__ log_delta,
    const float* __restrict__ log_r,
    float* __restrict__ out,
    int num_series, int F)
{
    const int g    = (int)((blockIdx.x * blockDim.x + threadIdx.x) >> 6);
    const int lane = (int)(threadIdx.x & 63);
    if (g >= num_series * NCHUNK) return;
    const int series = g / NCHUNK;
    const int c      = g - series * NCHUNK;   // chunk index in series
    const int f      = series % F;

    const float la = log_alpha[f], ld = log_delta[f], lr = log_r[f];
    const bool  triv = (la == 0.0f) && (ld == 0.0f) && (lr == 0.0f);

    const float s    = __expf(log_s[f]);
    const float oms  = 1.0f - s;
    const float oms2 = oms * oms;
    const float oms4 = oms2 * oms2;        // per-lane (4-elem) decay

    // A256 = oms4^64 = oms^256 (sub-chunk decay); A1024 = chunk decay
    float A256 = oms4;
    #pragma unroll
    for (int i = 0; i < 6; ++i) A256 *= A256;
    float A1024 = A256 * A256; A1024 *= A1024;
    const bool decay_ok = fabsf(A1024) < 1e-7f;  // one warm chunk suffices

    const float Apow4 = ipow6(oms4, lane);       // oms4^lane

    const float4* __restrict__ xb = (const float4*)(x + (size_t)series * TLEN);
    float4* __restrict__ ob       = (float4*)(out + (size_t)series * TLEN);

    const int cb = c * CHUNK_V4;           // main-chunk float4 base
    const int wb = cb - CHUNK_V4;          // warm-chunk float4 base (c>0)

    // ---- issue ALL loads up front: 4 warm + 4 main, one independent burst ----
    float4 wq[4], q[4];
    if (c > 0) {                           // warm chunk always fully in-bounds
        #pragma unroll
        for (int j = 0; j < 4; ++j) wq[j] = xb[wb + SUB_V4 * j + lane];
    }
    #pragma unroll
    for (int j = 0; j < 4; ++j) {
        const int vi = cb + SUB_V4 * j + lane;
        q[j] = (vi < NV4) ? xb[vi] : make_float4(0.f, 0.f, 0.f, 0.f);
    }

    // ---- main B-chains (independent of warm path) ----
    float S[4];
    #pragma unroll
    for (int j = 0; j < 4; ++j) {
        const float c0 = (c == 0 && j == 0 && lane == 0) ? 1.0f : s;
        float b = c0 * q[j].x;
        b = fmaf(oms, b, s * q[j].y);
        b = fmaf(oms, b, s * q[j].z);
        b = fmaf(oms, b, s * q[j].w);
        S[j] = b;
    }

    // ---- warm-chunk reduction -> Mc (carry entering this chunk) ----
    float Mc = 0.0f;
    if (c > 0) {
        const float wl = ipow6(oms4, 63 - lane);
        if (decay_ok) {
            float Bw[4];
            #pragma unroll
            for (int k = 0; k < 4; ++k) {
                float b = s * wq[k].x;
                b = fmaf(oms, b, s * wq[k].y);
                b = fmaf(oms, b, s * wq[k].z);
                b = fmaf(oms, b, s * wq[k].w);
                Bw[k] = b;
            }
            float v = wl * fmaf(A256, fmaf(A256, fmaf(A256, Bw[0], Bw[1]), Bw[2]), Bw[3]);
            #pragma unroll
            for (int off = 1; off < 64; off <<= 1) v += __shfl_xor(v, off, 64);
            Mc = v;
        } else {
            // exact fallback: accumulate all earlier chunks (rare; decay too slow)
            for (int wc = 0; wc < c; ++wc) {
                float Bw[4];
                #pragma unroll
                for (int k = 0; k < 4; ++k) {
                    const float4 qw = xb[wc * CHUNK_V4 + SUB_V4 * k + lane];
                    const float c0 = (wc == 0 && k == 0 && lane == 0) ? 1.0f : s;
                    float b = c0 * qw.x;
                    b = fmaf(oms, b, s * qw.y);
                    b = fmaf(oms, b, s * qw.z);
                    b = fmaf(oms, b, s * qw.w);
                    Bw[k] = b;
                }
                float v = wl * fmaf(A256, fmaf(A256, fmaf(A256, Bw[0], Bw[1]), Bw[2]), Bw[3]);
                #pragma unroll
                for (int off = 1; off < 64; off <<= 1) v += __shfl_xor(v, off, 64);
                Mc = fmaf(A1024, Mc, v);
            }
        }
    }

    // ---- 4 constant-coefficient Kogge-Stone scans (interleaved per level) ----
    float w = oms4;
    #pragma unroll
    for (int off = 1; off < 64; off <<= 1) {
        #pragma unroll
        for (int j = 0; j < 4; ++j) {
            const float Sp = __shfl_up(S[j], off, 64);
            if (lane >= off) S[j] = fmaf(w, Sp, S[j]);
        }
        w *= w;
    }

    // ---- parallel carry round + pure-FMA prefix across sub-chunks ----
    float T[3];
    #pragma unroll
    for (int j = 0; j < 3; ++j) T[j] = __shfl(S[j], 63, 64);
    float P[4];
    P[0] = Mc;
    #pragma unroll
    for (int j = 1; j < 4; ++j) P[j] = fmaf(A256, P[j - 1], T[j - 1]);

    // ---- epilogue: rerun recurrence seeded with per-sub-chunk entering M ----
    if (triv) {
        // alpha=delta=r=1  =>  out = x / (eps + M)
        #pragma unroll
        for (int j = 0; j < 4; ++j) {
            const int vi = cb + SUB_V4 * j + lane;
            const float Se = __shfl_up(S[j], 1, 64);
            const float Be = (lane == 0) ? 0.0f : Se;
            float m = fmaf(Apow4, P[j], Be);
            if (vi < NV4) {
                const float c0 = (c == 0 && j == 0 && lane == 0) ? 1.0f : s;
                float4 o;
                m = fmaf(oms, m, c0 * q[j].x); o.x = q[j].x * __builtin_amdgcn_rcpf(m + EPS);
                m = fmaf(oms, m, s  * q[j].y); o.y = q[j].y * __builtin_amdgcn_rcpf(m + EPS);
                m = fmaf(oms, m, s  * q[j].z); o.z = q[j].z * __builtin_amdgcn_rcpf(m + EPS);
                m = fmaf(oms, m, s  * q[j].w); o.w = q[j].w * __builtin_amdgcn_rcpf(m + EPS);
                ob[vi] = o;
            }
        }
    } else {
        const float alpha  = __expf(la);
        const float delta  = __expf(ld);
        const float r      = __expf(lr);
        const float deltar = __powf(delta, lr == 0.0f ? 1.0f : r);
        #pragma unroll
        for (int j = 0; j < 4; ++j) {
            const int vi = cb + SUB_V4 * j + lane;
            const float Se = __shfl_up(S[j], 1, 64);
            const float Be = (lane == 0) ? 0.0f : Se;
            float m = fmaf(Apow4, P[j], Be);
            if (vi < NV4) {
                const float c0 = (c == 0 && j == 0 && lane == 0) ? 1.0f : s;
                float4 o;
                m = fmaf(oms, m, c0 * q[j].x); o.x = pcen_full(q[j].x, m, alpha, delta, r, deltar);
                m = fmaf(oms, m, s  * q[j].y); o.y = pcen_full(q[j].y, m, alpha, delta, r, deltar);
                m = fmaf(oms, m, s  * q[j].z); o.z = pcen_full(q[j].z, m, alpha, delta, r, deltar);
                m = fmaf(oms, m, s  * q[j].w); o.w = pcen_full(q[j].w, m, alpha, delta, r, deltar);
                ob[vi] = o;
            }
        }
    }
}

extern "C" void kernel_launch(void* const* d_in, const int* in_sizes, int n_in,
                              void* d_out, int out_size, void* d_ws, size_t ws_size,
                              hipStream_t stream) {
    const float* x         = (const float*)d_in[0];
    const float* log_s     = (const float*)d_in[1];
    const float* log_alpha = (const float*)d_in[2];
    const float* log_delta = (const float*)d_in[3];
    const float* log_r     = (const float*)d_in[4];
    float* out             = (float*)d_out;

    const int F = in_sizes[1];                  // 128 bands
    const int num_series = in_sizes[0] / TLEN;  // 4096
    const int num_waves  = num_series * NCHUNK; // one wave per chunk
    const int num_threads = num_waves * 64;
    const int grid = (num_threads + 255) / 256;

    pcen_kernel<<<grid, 256, 0, stream>>>(x, log_s, log_alpha, log_delta, log_r,
                                          out, num_series, F);
}